// Round 10
// baseline (113.964 us; speedup 1.0000x reference)
//
#include <hip/hip_runtime.h>
#include <hip/hip_bf16.h>

typedef short bf16x8 __attribute__((ext_vector_type(8)));
typedef float f32x4 __attribute__((ext_vector_type(4)));
typedef long l64x2 __attribute__((ext_vector_type(2)));
typedef unsigned short u16;
typedef unsigned char u8;

#define NB2 (-0.35f * 1.44269504088896340736f)
#define P2C (0.70f * 1.44269504088896340736f)
#define MFP8(a,b,c) __builtin_amdgcn_mfma_f32_16x16x32_fp8_fp8(a, b, c, 0, 0, 0)
#define MFBF(a,b,c) __builtin_amdgcn_mfma_f32_16x16x32_bf16(a, b, c, 0, 0, 0)

__device__ __forceinline__ u16 f2bf(float f) {
  union { float f; unsigned int u; } v; v.f = f;
  unsigned int x = v.u;
  return (u16)((x + 0x7FFFu + ((x >> 16) & 1u)) >> 16);
}

__device__ __forceinline__ unsigned cvtpk(float lo, float hi) {
  unsigned r;
  asm("v_cvt_pk_bf16_f32 %0, %1, %2" : "=v"(r) : "v"(lo), "v"(hi));
  return r;
}

__device__ __forceinline__ u8 f2e4m3(float f) {
  unsigned int u = __float_as_uint(f);
  u8 s = (u8)((u >> 24) & 0x80u);
  float a = fabsf(f);
  if (a >= 448.f) return s | 0x7E;
  if (a < 0.015625f) return s | (u8)(int)rintf(a * 512.f);
  unsigned int m = u & 0x7fffffffu;
  unsigned int r = m + 0x7FFFFu + ((m >> 20) & 1u);
  return s | (u8)((((r >> 23) - 120u) << 3) | ((r >> 20) & 7u));
}

__device__ __forceinline__ unsigned int pk4(float a, float b, float c, float d) {
#if __has_builtin(__builtin_amdgcn_cvt_pk_fp8_f32)
  int v = __builtin_amdgcn_cvt_pk_fp8_f32(a, b, 0, false);
  v = __builtin_amdgcn_cvt_pk_fp8_f32(c, d, v, true);
  return (unsigned int)v;
#else
  return (unsigned int)f2e4m3(a) | ((unsigned int)f2e4m3(b) << 8)
       | ((unsigned int)f2e4m3(c) << 16) | ((unsigned int)f2e4m3(d) << 24);
#endif
}

#define GLOAD_LDS(g, l) __builtin_amdgcn_global_load_lds( \
    (const __attribute__((address_space(1))) unsigned int*)(g), \
    (__attribute__((address_space(3))) unsigned int*)(l), 16, 0, 0)

// ---------- prep: x fp32 rows -> fp8 rows + row sum-of-squares ----------
__global__ __launch_bounds__(512)
void prep_x8(const float* __restrict__ src, u8* __restrict__ dst,
             float* __restrict__ sq) {
  const int row = blockIdx.x * 8 + (threadIdx.x >> 6);
  const int lane = threadIdx.x & 63;
  const float4* p = (const float4*)(src + (size_t)row * 512) + lane * 2;
  float4 a = p[0], b = p[1];
  float ss = a.x*a.x + a.y*a.y + a.z*a.z + a.w*a.w
           + b.x*b.x + b.y*b.y + b.z*b.z + b.w*b.w;
  uint2 o;
  o.x = pk4(a.x, a.y, a.z, a.w);
  o.y = pk4(b.x, b.y, b.z, b.w);
  ((uint2*)(dst + (size_t)row * 512))[lane] = o;
  ss += __shfl_xor(ss, 1);  ss += __shfl_xor(ss, 2);
  ss += __shfl_xor(ss, 4);  ss += __shfl_xor(ss, 8);
  ss += __shfl_xor(ss, 16); ss += __shfl_xor(ss, 32);
  if (lane == 0) sq[row] = ss;
}

// ---------- prep: centers -> fp8 frag-stream in 32-center chunks + csq ----------
// chunk = c>>5; within: [sl(4)][32c][128B]; unit u = (lg*2 + (s>>1)) ^ (c&7);
// element k = sl*128 + s*32 + lg*8, stored at u*16 + (s&1)*8.
__global__ __launch_bounds__(256)
void prep_cen(const float* __restrict__ cen, u8* __restrict__ cfr,
              float* __restrict__ csq) {
  const int t = threadIdx.x;
  const int c = blockIdx.x * 4 + (t >> 6);
  const int i6 = t & 63;                  // sl*16 + s*4 + lg
  const int sl = i6 >> 4, s = (i6 >> 2) & 3, lg = i6 & 3;
  const float* p = cen + (size_t)c * 512 + i6 * 8;
  float4 a = *(const float4*)p, b = *(const float4*)(p + 4);
  float ss = a.x*a.x + a.y*a.y + a.z*a.z + a.w*a.w
           + b.x*b.x + b.y*b.y + b.z*b.z + b.w*b.w;
  uint2 o;
  o.x = pk4(a.x, a.y, a.z, a.w);
  o.y = pk4(b.x, b.y, b.z, b.w);
  const int u = (lg * 2 + (s >> 1)) ^ (c & 7);
  *(uint2*)(cfr + (size_t)(c >> 5) * 16384 + sl * 4096 + (c & 31) * 128
            + u * 16 + (s & 1) * 8) = o;
  ss += __shfl_xor(ss, 1);  ss += __shfl_xor(ss, 2);
  ss += __shfl_xor(ss, 4);  ss += __shfl_xor(ss, 8);
  ss += __shfl_xor(ss, 16); ss += __shfl_xor(ss, 32);
  if (i6 == 0) csq[c] = ss;
}

// ---------- prep: W [4096][128] f32 -> chunk-major bf16 [chunk(128)][o(128)][32c swz] ----------
// element (o,c): byte = (c>>5)*8192 + o*64 + ((((c&31)>>3) ^ ((o>>1)&3))*16) + (c&7)*2
__global__ __launch_bounds__(256)
void prep_w(const float* __restrict__ W, u8* __restrict__ wt) {
  __shared__ u16 t_[128 * 66];
  const int c0 = blockIdx.x * 64;
  const int t = threadIdx.x;
#pragma unroll
  for (int it = 0; it < 32; ++it) {
    int idx = it * 256 + t;
    int cl = idx >> 7;
    int o  = idx & 127;
    t_[o * 66 + cl] = f2bf(W[(size_t)(c0 + cl) * 128 + o]);
  }
  __syncthreads();
#pragma unroll
  for (int it = 0; it < 4; ++it) {
    int idx = it * 256 + t;            // 0..1023 : 16B units
    int o  = idx >> 3;
    int uu = idx & 7;
    int ch = uu >> 2;                  // local chunk 0/1
    int g  = uu & 3;                   // c-granule of 8
    int u  = g ^ ((o >> 1) & 3);
    u16* d = (u16*)(wt + ((size_t)(c0 >> 5) + ch) * 8192 + o * 64 + u * 16);
    const u16* s_ = &t_[o * 66 + ch * 32 + g * 8];
#pragma unroll
    for (int j = 0; j < 8; ++j) d[j] = s_[j];
  }
}

// ---------- init: out = bias ----------
__global__ __launch_bounds__(256)
void init_out(const float* __restrict__ bias, float* __restrict__ out) {
  const int i4 = blockIdx.x * 256 + threadIdx.x;
  float4 b = ((const float4*)bias)[i4 & 31];
  ((float4*)out)[i4] = b;
}

// ---------- main: 512 blocks = 128 row-tiles(128) x 4 quarters(1024c); 2 blocks/CU ----------
// Swapped GEMM1 (centers=A, x=B) -> P in registers (cvt_pk + ds_bpermute) -> GEMM2.
__global__ __launch_bounds__(512, 4)
void rbf_main(const u8* __restrict__ xq8, const u8* __restrict__ cfr,
              const u8* __restrict__ wtgb, const float* __restrict__ csq_g,
              const float* __restrict__ xsq_g, float* __restrict__ out)
{
  __shared__ __align__(16) u8  cs[2][16384];   // center chunk dbuf (32c x 512k fp8)
  __shared__ __align__(16) u8  wt[2][8192];    // W chunk dbuf [128o][32c] bf16 swz
  __shared__ __align__(16) float csq_l[1024];
  __shared__ __align__(16) float xsq_l[128];

  const int tid = threadIdx.x;
  const int lane = tid & 63;
  const int mw = tid >> 6;                 // wave 0..7 -> rows mw*16..+16
  const int l15 = lane & 15;
  const int lg = lane >> 4;
  const int bid = blockIdx.x;
  const int chq = bid & 3;                 // center quarter
  const size_t r0 = (size_t)(bid >> 2) * 128;

#define S_CS(cc) do { \
    const u8* sG_ = cfr + ((size_t)(chq * 32 + (cc)) << 14) + tid * 16; \
    u8* sL_ = &cs[(cc) & 1][0] + tid * 16; \
    GLOAD_LDS(sG_,        sL_); \
    GLOAD_LDS(sG_ + 8192, sL_ + 8192); \
  } while (0)

#define S_W(cc) do { \
    GLOAD_LDS(wtgb + ((size_t)(chq * 32 + (cc)) << 13) + tid * 16, \
              &wt[(cc) & 1][0] + tid * 16); \
  } while (0)

  // prologue staging
  if (tid < 32)  GLOAD_LDS(xsq_g + r0 + tid * 4, xsq_l + tid * 4);
  if (tid < 256) GLOAD_LDS(csq_g + chq * 1024 + tid * 4, csq_l + tid * 4);
  S_CS(0);
  S_W(0);

  // x fragments (fp8, B-operand: lane l15 = m-row) -> registers
  long xf[16];
  {
    const u8* xr = xq8 + (r0 + mw * 16 + l15) * 512 + lg * 8;
#pragma unroll
    for (int ks = 0; ks < 16; ++ks)
      xf[ks] = *(const long*)(xr + ks * 32);
  }

  asm volatile("s_waitcnt vmcnt(0)" ::: "memory");
  __builtin_amdgcn_s_barrier();
  __builtin_amdgcn_sched_barrier(0);

  const float xq = xsq_l[mw * 16 + l15];
  const float xn = NB2 * xq;

  // LDS byte-offset bases (octet-conflict-free by construction)
  const int cbase = l15 * 128 + (((lg * 2) ^ (l15 & 7)) << 4);     // GEMM1 A (centers)
  const int wbase = l15 * 64 + ((lg ^ ((l15 >> 1) & 3)) << 4);     // GEMM2 B (W), +ot*1024
  // bpermute source-lane byte addresses for P-frag assembly
  const int a01 = ((((lg * 2) & 3) * 16) + l15) * 4;
  const int a23 = ((((lg * 2 + 1) & 3) * 16) + l15) * 4;
  const bool hi2 = (lg & 2) != 0;

  const f32x4 z4 = {0.f, 0.f, 0.f, 0.f};
  f32x4 sacc[2] = {z4, z4};
  f32x4 oa[8] = {z4, z4, z4, z4, z4, z4, z4, z4};

#pragma unroll 1
  for (int cc = 0; cc < 32; ++cc) {
    if (cc < 31) { S_CS(cc + 1); S_W(cc + 1); }
    const u8* csb = &cs[cc & 1][0];

    // ---- GEMM1 (swapped): S^T tiles, A=centers(LDS), B=x(regs) ----
#pragma unroll
    for (int sl = 0; sl < 4; ++sl) {
      l64x2 A00 = *(const l64x2*)(csb + sl * 4096 + cbase);            // c0..15, slots s0/s1
      l64x2 A01 = *(const l64x2*)(csb + sl * 4096 + (cbase ^ 16));     // c0..15, s2/s3
      l64x2 A10 = *(const l64x2*)(csb + sl * 4096 + 2048 + cbase);     // c16..31
      l64x2 A11 = *(const l64x2*)(csb + sl * 4096 + 2048 + (cbase ^ 16));
      __builtin_amdgcn_s_setprio(1);
      sacc[0] = MFP8(A00[0], xf[sl * 4 + 0], sacc[0]);
      sacc[1] = MFP8(A10[0], xf[sl * 4 + 0], sacc[1]);
      sacc[0] = MFP8(A00[1], xf[sl * 4 + 1], sacc[0]);
      sacc[1] = MFP8(A10[1], xf[sl * 4 + 1], sacc[1]);
      sacc[0] = MFP8(A01[0], xf[sl * 4 + 2], sacc[0]);
      sacc[1] = MFP8(A11[0], xf[sl * 4 + 2], sacc[1]);
      sacc[0] = MFP8(A01[1], xf[sl * 4 + 3], sacc[0]);
      sacc[1] = MFP8(A11[1], xf[sl * 4 + 3], sacc[1]);
      __builtin_amdgcn_s_setprio(0);
    }

    // ---- rbf in registers: lane l15 = m, reg (ct,r) = c = ct*16+lg*4+r ----
    f32x4 cq0v = *(const f32x4*)(csq_l + cc * 32 + lg * 4);
    f32x4 cq1v = *(const f32x4*)(csq_l + cc * 32 + 16 + lg * 4);
    float e00 = __builtin_amdgcn_exp2f(fmaf(sacc[0][0], P2C, fmaf(cq0v[0], NB2, xn)));
    float e01 = __builtin_amdgcn_exp2f(fmaf(sacc[0][1], P2C, fmaf(cq0v[1], NB2, xn)));
    float e02 = __builtin_amdgcn_exp2f(fmaf(sacc[0][2], P2C, fmaf(cq0v[2], NB2, xn)));
    float e03 = __builtin_amdgcn_exp2f(fmaf(sacc[0][3], P2C, fmaf(cq0v[3], NB2, xn)));
    float e10 = __builtin_amdgcn_exp2f(fmaf(sacc[1][0], P2C, fmaf(cq1v[0], NB2, xn)));
    float e11 = __builtin_amdgcn_exp2f(fmaf(sacc[1][1], P2C, fmaf(cq1v[1], NB2, xn)));
    float e12 = __builtin_amdgcn_exp2f(fmaf(sacc[1][2], P2C, fmaf(cq1v[2], NB2, xn)));
    float e13 = __builtin_amdgcn_exp2f(fmaf(sacc[1][3], P2C, fmaf(cq1v[3], NB2, xn)));
    sacc[0] = z4; sacc[1] = z4;

    // pack to bf16 pairs (consecutive c) and redistribute to A-frag k-layout
    unsigned wA0 = cvtpk(e00, e01), wB0 = cvtpk(e02, e03);
    unsigned wA1 = cvtpk(e10, e11), wB1 = cvtpk(e12, e13);
    int t0a = __builtin_amdgcn_ds_bpermute(a01, (int)wA0);
    int t0b = __builtin_amdgcn_ds_bpermute(a01, (int)wA1);
    int t1a = __builtin_amdgcn_ds_bpermute(a01, (int)wB0);
    int t1b = __builtin_amdgcn_ds_bpermute(a01, (int)wB1);
    int t2a = __builtin_amdgcn_ds_bpermute(a23, (int)wA0);
    int t2b = __builtin_amdgcn_ds_bpermute(a23, (int)wA1);
    int t3a = __builtin_amdgcn_ds_bpermute(a23, (int)wB0);
    int t3b = __builtin_amdgcn_ds_bpermute(a23, (int)wB1);
    union { int i[4]; bf16x8 v; } pu;
    pu.i[0] = hi2 ? t0b : t0a;
    pu.i[1] = hi2 ? t1b : t1a;
    pu.i[2] = hi2 ? t2b : t2a;
    pu.i[3] = hi2 ? t3b : t3a;
    bf16x8 pf = pu.v;

    // ---- GEMM2: A = P (regs), B = W (LDS); D rows = m, cols = o ----
    {
      const u8* wtb = &wt[cc & 1][0];
      bf16x8 w0 = *(const bf16x8*)(wtb + wbase);
      bf16x8 w1 = *(const bf16x8*)(wtb + wbase + 1024);
      bf16x8 w2 = *(const bf16x8*)(wtb + wbase + 2048);
      bf16x8 w3 = *(const bf16x8*)(wtb + wbase + 3072);
      __builtin_amdgcn_s_setprio(1);
      oa[0] = MFBF(pf, w0, oa[0]);
      oa[1] = MFBF(pf, w1, oa[1]);
      oa[2] = MFBF(pf, w2, oa[2]);
      oa[3] = MFBF(pf, w3, oa[3]);
      __builtin_amdgcn_s_setprio(0);
      bf16x8 w4 = *(const bf16x8*)(wtb + wbase + 4096);
      bf16x8 w5 = *(const bf16x8*)(wtb + wbase + 5120);
      bf16x8 w6 = *(const bf16x8*)(wtb + wbase + 6144);
      bf16x8 w7 = *(const bf16x8*)(wtb + wbase + 7168);
      __builtin_amdgcn_s_setprio(1);
      oa[4] = MFBF(pf, w4, oa[4]);
      oa[5] = MFBF(pf, w5, oa[5]);
      oa[6] = MFBF(pf, w6, oa[6]);
      oa[7] = MFBF(pf, w7, oa[7]);
      __builtin_amdgcn_s_setprio(0);
    }

    asm volatile("s_waitcnt vmcnt(0)" ::: "memory");
    __builtin_amdgcn_s_barrier();
    __builtin_amdgcn_sched_barrier(0);
  }

  // epilogue: out += partial (bias added by init_out); D: rows m=lg*4+r, cols o=ot*16+l15
#pragma unroll
  for (int ot = 0; ot < 8; ++ot) {
#pragma unroll
    for (int r = 0; r < 4; ++r) {
      const int m = mw * 16 + lg * 4 + r;
      atomicAdd(&out[(r0 + m) * 128 + ot * 16 + l15], oa[ot][r]);
    }
  }
#undef S_CS
#undef S_W
}

extern "C" void kernel_launch(void* const* d_in, const int* in_sizes, int n_in,
                              void* d_out, int out_size, void* d_ws, size_t ws_size,
                              hipStream_t stream) {
  (void)in_sizes; (void)n_in; (void)out_size; (void)ws_size;
  const float* x   = (const float*)d_in[0];
  const float* cen = (const float*)d_in[1];
  const float* W   = (const float*)d_in[2];
  const float* b   = (const float*)d_in[3];
  u8* xq8 = (u8*)d_ws;                          // 16384*512 = 8 MB
  u8* cfr = xq8 + (size_t)16384 * 512;          // 4096*512  = 2 MB (frag stream)
  u8* wtgb = cfr + (size_t)4096 * 512;          // 128*4096 bf16 = 1 MB (chunk-major)
  float* csq = (float*)(wtgb + (size_t)128 * 4096 * 2);  // 16 KB
  float* xsq = csq + 4096;                      // 64 KB
  prep_x8<<<2048, 512, 0, stream>>>(x, xq8, xsq);
  prep_cen<<<1024, 256, 0, stream>>>(cen, cfr, csq);
  prep_w<<<64, 256, 0, stream>>>(W, wtgb);
  init_out<<<2048, 256, 0, stream>>>(b, (float*)d_out);
  rbf_main<<<512, 512, 0, stream>>>(xq8, cfr, wtgb, csq, xsq, (float*)d_out);
}

// Round 11
// 105.748 us; speedup vs baseline: 1.0777x; 1.0777x over previous
//
#include <hip/hip_runtime.h>
#include <hip/hip_bf16.h>

typedef short bf16x8 __attribute__((ext_vector_type(8)));
typedef float f32x4 __attribute__((ext_vector_type(4)));
typedef float f32x16 __attribute__((ext_vector_type(16)));
typedef long l64x2 __attribute__((ext_vector_type(2)));
typedef unsigned short u16;
typedef unsigned char u8;

#define NB2 (-0.35f * 1.44269504088896340736f)
#define P2C (0.70f * 1.44269504088896340736f)
#define MF8(a,b,c)  __builtin_amdgcn_mfma_f32_32x32x16_fp8_fp8(a, b, c, 0, 0, 0)
#define MFB(a,b,c)  __builtin_amdgcn_mfma_f32_32x32x16_bf16(a, b, c, 0, 0, 0)

__device__ __forceinline__ u16 f2bf(float f) {
  union { float f; unsigned int u; } v; v.f = f;
  unsigned int x = v.u;
  return (u16)((x + 0x7FFFu + ((x >> 16) & 1u)) >> 16);
}

__device__ __forceinline__ unsigned cvtpk(float lo, float hi) {
  unsigned r;
  asm("v_cvt_pk_bf16_f32 %0, %1, %2" : "=v"(r) : "v"(lo), "v"(hi));
  return r;
}

// exchange a.hi-lanes <-> b.lo-lanes
__device__ __forceinline__ void pswap(unsigned &a, unsigned &b) {
  asm volatile("v_permlane32_swap_b32 %0, %1" : "+v"(a), "+v"(b));
}

__device__ __forceinline__ u8 f2e4m3(float f) {
  unsigned int u = __float_as_uint(f);
  u8 s = (u8)((u >> 24) & 0x80u);
  float a = fabsf(f);
  if (a >= 448.f) return s | 0x7E;
  if (a < 0.015625f) return s | (u8)(int)rintf(a * 512.f);
  unsigned int m = u & 0x7fffffffu;
  unsigned int r = m + 0x7FFFFu + ((m >> 20) & 1u);
  return s | (u8)((((r >> 23) - 120u) << 3) | ((r >> 20) & 7u));
}

__device__ __forceinline__ unsigned int pk4(float a, float b, float c, float d) {
#if __has_builtin(__builtin_amdgcn_cvt_pk_fp8_f32)
  int v = __builtin_amdgcn_cvt_pk_fp8_f32(a, b, 0, false);
  v = __builtin_amdgcn_cvt_pk_fp8_f32(c, d, v, true);
  return (unsigned int)v;
#else
  return (unsigned int)f2e4m3(a) | ((unsigned int)f2e4m3(b) << 8)
       | ((unsigned int)f2e4m3(c) << 16) | ((unsigned int)f2e4m3(d) << 24);
#endif
}

#define GLOAD_LDS(g, l) __builtin_amdgcn_global_load_lds( \
    (const __attribute__((address_space(1))) unsigned int*)(g), \
    (__attribute__((address_space(3))) unsigned int*)(l), 16, 0, 0)

// ---------- prep: x -> fp8 frag-stream [rowtile(512)][p(16)][lane(64)]16B + xsq ----------
// lane unit (p,l): row m = l&31, h = l>>5; bytes = k{2p*16+h*8..+8} ++ k{(2p+1)*16+h*8..+8}
__global__ __launch_bounds__(512)
void prep_x8(const float* __restrict__ src, u8* __restrict__ dst,
             float* __restrict__ sq) {
  const int row = blockIdx.x * 8 + (threadIdx.x >> 6);
  const int i6 = threadIdx.x & 63;            // k granule: k in [i6*8, i6*8+8)
  const float4* p = (const float4*)(src + (size_t)row * 512) + i6 * 2;
  float4 a = p[0], b = p[1];
  float ss = a.x*a.x + a.y*a.y + a.z*a.z + a.w*a.w
           + b.x*b.x + b.y*b.y + b.z*b.z + b.w*b.w;
  uint2 o;
  o.x = pk4(a.x, a.y, a.z, a.w);
  o.y = pk4(b.x, b.y, b.z, b.w);
  const int pp = i6 >> 2, sub = (i6 >> 1) & 1, h = i6 & 1;
  const int l = (h << 5) | (row & 31);
  *(uint2*)(dst + (size_t)(row >> 5) * 16384 + pp * 1024 + l * 16 + sub * 8) = o;
  ss += __shfl_xor(ss, 1);  ss += __shfl_xor(ss, 2);
  ss += __shfl_xor(ss, 4);  ss += __shfl_xor(ss, 8);
  ss += __shfl_xor(ss, 16); ss += __shfl_xor(ss, 32);
  if (i6 == 0) sq[row] = ss;
}

// ---------- prep: centers -> fp8 frag-stream [chunk(128)][p(16)][cgrp(4)][swz unit(16)]16B + csq ----------
// read addr (lane c=l&31,h=l>>5): p*1024 + (c>>3)*256 + ((((c&7)*2+h)^((c>>2)&1)))*16
__global__ __launch_bounds__(256)
void prep_cen(const float* __restrict__ cen, u8* __restrict__ cfr,
              float* __restrict__ csq) {
  const int t = threadIdx.x;
  const int c = blockIdx.x * 4 + (t >> 6);
  const int i6 = t & 63;
  const float* p = cen + (size_t)c * 512 + i6 * 8;
  float4 a = *(const float4*)p, b = *(const float4*)(p + 4);
  float ss = a.x*a.x + a.y*a.y + a.z*a.z + a.w*a.w
           + b.x*b.x + b.y*b.y + b.z*b.z + b.w*b.w;
  uint2 o;
  o.x = pk4(a.x, a.y, a.z, a.w);
  o.y = pk4(b.x, b.y, b.z, b.w);
  const int pp = i6 >> 2, sub = (i6 >> 1) & 1, h = i6 & 1;
  const int lc = c & 31;
  const int v = (((lc & 7) * 2 + h) ^ ((lc >> 2) & 1));
  *(uint2*)(cfr + (size_t)(c >> 5) * 16384 + pp * 1024 + (lc >> 3) * 256
            + v * 16 + sub * 8) = o;
  ss += __shfl_xor(ss, 1);  ss += __shfl_xor(ss, 2);
  ss += __shfl_xor(ss, 4);  ss += __shfl_xor(ss, 8);
  ss += __shfl_xor(ss, 16); ss += __shfl_xor(ss, 32);
  if (i6 == 0) csq[c] = ss;
}

// ---------- prep: W [4096][128] f32 -> chunk-major bf16 units ----------
// element (o,c): byte = (c>>5)*8192 + o*64 + (((((c&31)>>4)*2 + ((c>>3)&1)) ^ ((o>>1)&3)))*16 + (c&7)*2
__global__ __launch_bounds__(256)
void prep_w(const float* __restrict__ W, u8* __restrict__ wt) {
  __shared__ u16 t_[128 * 66];
  const int c0 = blockIdx.x * 64;
  const int t = threadIdx.x;
#pragma unroll
  for (int it = 0; it < 32; ++it) {
    int idx = it * 256 + t;
    int cl = idx >> 7;
    int o  = idx & 127;
    t_[o * 66 + cl] = f2bf(W[(size_t)(c0 + cl) * 128 + o]);
  }
  __syncthreads();
#pragma unroll
  for (int it = 0; it < 4; ++it) {
    int idx = it * 256 + t;            // 0..1023 : 16B units
    int o  = idx >> 3;
    int uu = idx & 7;
    int ch = uu >> 2;                  // local chunk 0/1
    int kt = (uu >> 1) & 1;
    int h2 = uu & 1;
    int u  = (kt * 2 + h2) ^ ((o >> 1) & 3);
    u16* d = (u16*)(wt + ((size_t)(c0 >> 5) + ch) * 8192 + o * 64 + u * 16);
    const u16* s_ = &t_[o * 66 + ch * 32 + kt * 16 + h2 * 8];
#pragma unroll
    for (int j = 0; j < 8; ++j) d[j] = s_[j];
  }
}

// ---------- init: out = bias ----------
__global__ __launch_bounds__(256)
void init_out(const float* __restrict__ bias, float* __restrict__ out) {
  const int i4 = blockIdx.x * 256 + threadIdx.x;
  float4 b = ((const float4*)bias)[i4 & 31];
  ((float4*)out)[i4] = b;
}

// ---------- main: 512 blocks(256thr) = 128 row-tiles(128r) x 4 quarters ----------
// 4 waves x 32 rows; 32x32x16 MFMAs; P fully in-register via cvt_pk + permlane32_swap.
__global__ __launch_bounds__(256, 2)
void rbf_main(const u8* __restrict__ xfs, const u8* __restrict__ cfr,
              const u8* __restrict__ wtgb, const float* __restrict__ csq_g,
              const float* __restrict__ xsq_g, float* __restrict__ out)
{
  __shared__ __align__(16) u8 cs[2][16384];   // center chunk dbuf (32c x 512k fp8 stream)
  __shared__ __align__(16) u8 wt[2][8192];    // W chunk dbuf [128o][32c] bf16 units
  __shared__ __align__(16) float csq_l[1024];
  __shared__ __align__(16) float xsq_l[128];

  const int tid = threadIdx.x;
  const int lane = tid & 63;
  const int wv = tid >> 6;                 // wave 0..3 -> rows wv*32..+32
  const int l31 = lane & 31;
  const int h = lane >> 5;
  const int bid = blockIdx.x;
  const int chq = bid & 3;
  const size_t r0 = (size_t)(bid >> 2) * 128;

#define S_CS(cc) do { \
    const u8* sG_ = cfr + ((size_t)(chq * 32 + (cc)) << 14) + tid * 16; \
    u8* sL_ = &cs[(cc) & 1][0] + tid * 16; \
    GLOAD_LDS(sG_,         sL_); \
    GLOAD_LDS(sG_ + 4096,  sL_ + 4096); \
    GLOAD_LDS(sG_ + 8192,  sL_ + 8192); \
    GLOAD_LDS(sG_ + 12288, sL_ + 12288); \
  } while (0)

#define S_W(cc) do { \
    const u8* wg_ = wtgb + ((size_t)(chq * 32 + (cc)) << 13) + tid * 16; \
    u8* wl_ = &wt[(cc) & 1][0] + tid * 16; \
    GLOAD_LDS(wg_,        wl_); \
    GLOAD_LDS(wg_ + 4096, wl_ + 4096); \
  } while (0)

  // prologue staging
  if (tid < 32) GLOAD_LDS(xsq_g + r0 + tid * 4, xsq_l + tid * 4);
  GLOAD_LDS(csq_g + chq * 1024 + tid * 4, csq_l + tid * 4);
  S_CS(0);
  S_W(0);

  // x fragments: 16 x b128 coalesced from frag-stream
  l64x2 xf[16];
  {
    const u8* xb = xfs + ((size_t)((bid >> 2) * 4 + wv)) * 16384 + lane * 16;
#pragma unroll
    for (int p = 0; p < 16; ++p)
      xf[p] = *(const l64x2*)(xb + p * 1024);
  }

  asm volatile("s_waitcnt vmcnt(0)" ::: "memory");
  __builtin_amdgcn_s_barrier();
  __builtin_amdgcn_sched_barrier(0);

  const float xn = NB2 * xsq_l[wv * 32 + l31];

  // LDS read bases (octet-distinct bank quads by construction)
  const int cbase = ((l31 >> 3) & 3) * 256
                  + ((((l31 & 7) * 2 + h) ^ ((l31 >> 2) & 1)) << 4);
  const int wsw = (l31 >> 1) & 3;
  const int wb_o = l31 * 64;
  const int wu0 = ((0 + h) ^ wsw) << 4;   // kt=0
  const int wu1 = ((2 + h) ^ wsw) << 4;   // kt=1

  const f32x16 z16 = {0,0,0,0,0,0,0,0,0,0,0,0,0,0,0,0};
  f32x16 oa0 = z16, oa1 = z16, oa2 = z16, oa3 = z16;

#pragma unroll 1
  for (int cc = 0; cc < 32; ++cc) {
    if (cc < 31) { S_CS(cc + 1); S_W(cc + 1); }
    const u8* csb = &cs[cc & 1][0];

    // ---- GEMM1 (swapped): D[c][m]; A=centers(LDS), B=x(regs); split-K 2 chains ----
    f32x16 s0 = z16, s1 = z16;
#pragma unroll
    for (int p = 0; p < 16; ++p) {
      l64x2 A = *(const l64x2*)(csb + p * 1024 + cbase);
      __builtin_amdgcn_s_setprio(1);
      if (p & 1) {
        s1 = MF8(A[0], xf[p][0], s1);
        s1 = MF8(A[1], xf[p][1], s1);
      } else {
        s0 = MF8(A[0], xf[p][0], s0);
        s0 = MF8(A[1], xf[p][1], s0);
      }
      __builtin_amdgcn_s_setprio(0);
    }

    // ---- rbf in registers: lane m=l31; reg r -> c = (r&3) + 8*(r>>2) + 4*h ----
    f32x4 cq0 = *(const f32x4*)(csq_l + cc * 32 + 0  + 4 * h);
    f32x4 cq1 = *(const f32x4*)(csq_l + cc * 32 + 8  + 4 * h);
    f32x4 cq2 = *(const f32x4*)(csq_l + cc * 32 + 16 + 4 * h);
    f32x4 cq3 = *(const f32x4*)(csq_l + cc * 32 + 24 + 4 * h);
    float e[16];
#pragma unroll
    for (int r = 0; r < 16; ++r) {
      const float cq = (r < 4 ? cq0[r] : r < 8 ? cq1[r - 4] : r < 12 ? cq2[r - 8] : cq3[r - 12]);
      e[r] = __builtin_amdgcn_exp2f(fmaf(s0[r] + s1[r], P2C, fmaf(cq, NB2, xn)));
    }
    // pack pairs (c, c+1) then half-exchange -> GEMM2 A-frags
    unsigned P0 = cvtpk(e[0],  e[1]),  P1 = cvtpk(e[2],  e[3]);
    unsigned P2 = cvtpk(e[4],  e[5]),  P3 = cvtpk(e[6],  e[7]);
    unsigned P4 = cvtpk(e[8],  e[9]),  P5 = cvtpk(e[10], e[11]);
    unsigned P6 = cvtpk(e[12], e[13]), P7 = cvtpk(e[14], e[15]);
    pswap(P0, P2); pswap(P1, P3);      // F: c 0..15   (F0=P0,F1=P1,F2=P2,F3=P3)
    pswap(P4, P6); pswap(P5, P7);      // G: c 16..31
    union { unsigned u[4]; bf16x8 v; } FA, GA;
    FA.u[0] = P0; FA.u[1] = P1; FA.u[2] = P2; FA.u[3] = P3;
    GA.u[0] = P4; GA.u[1] = P5; GA.u[2] = P6; GA.u[3] = P7;

    // ---- GEMM2: D[m][o] += P(32m x 32c) x W(32c x 128o) ----
    {
      const u8* wtb = &wt[cc & 1][0];
      bf16x8 wA0 = *(const bf16x8*)(wtb + wb_o + wu0);
      bf16x8 wB0 = *(const bf16x8*)(wtb + wb_o + wu1);
      bf16x8 wA1 = *(const bf16x8*)(wtb + 2048 + wb_o + wu0);
      bf16x8 wB1 = *(const bf16x8*)(wtb + 2048 + wb_o + wu1);
      __builtin_amdgcn_s_setprio(1);
      oa0 = MFB(FA.v, wA0, oa0);
      oa0 = MFB(GA.v, wB0, oa0);
      oa1 = MFB(FA.v, wA1, oa1);
      oa1 = MFB(GA.v, wB1, oa1);
      __builtin_amdgcn_s_setprio(0);
      bf16x8 wA2 = *(const bf16x8*)(wtb + 4096 + wb_o + wu0);
      bf16x8 wB2 = *(const bf16x8*)(wtb + 4096 + wb_o + wu1);
      bf16x8 wA3 = *(const bf16x8*)(wtb + 6144 + wb_o + wu0);
      bf16x8 wB3 = *(const bf16x8*)(wtb + 6144 + wb_o + wu1);
      __builtin_amdgcn_s_setprio(1);
      oa2 = MFB(FA.v, wA2, oa2);
      oa2 = MFB(GA.v, wB2, oa2);
      oa3 = MFB(FA.v, wA3, oa3);
      oa3 = MFB(GA.v, wB3, oa3);
      __builtin_amdgcn_s_setprio(0);
    }

    asm volatile("s_waitcnt vmcnt(0)" ::: "memory");
    __builtin_amdgcn_s_barrier();
    __builtin_amdgcn_sched_barrier(0);
  }

  // epilogue: out += partial; D rows m=(r&3)+8*(r>>2)+4h, cols o=t*32+l31
#pragma unroll
  for (int r = 0; r < 16; ++r) {
    const int m = wv * 32 + (r & 3) + 8 * (r >> 2) + 4 * h;
    float* op = &out[(r0 + m) * 128 + l31];
    atomicAdd(op,      oa0[r]);
    atomicAdd(op + 32, oa1[r]);
    atomicAdd(op + 64, oa2[r]);
    atomicAdd(op + 96, oa3[r]);
  }
#undef S_CS
#undef S_W
}

extern "C" void kernel_launch(void* const* d_in, const int* in_sizes, int n_in,
                              void* d_out, int out_size, void* d_ws, size_t ws_size,
                              hipStream_t stream) {
  (void)in_sizes; (void)n_in; (void)out_size; (void)ws_size;
  const float* x   = (const float*)d_in[0];
  const float* cen = (const float*)d_in[1];
  const float* W   = (const float*)d_in[2];
  const float* b   = (const float*)d_in[3];
  u8* xfs = (u8*)d_ws;                          // 16384*512 = 8 MB (x frag-stream)
  u8* cfr = xfs + (size_t)16384 * 512;          // 4096*512  = 2 MB (center frag-stream)
  u8* wtgb = cfr + (size_t)4096 * 512;          // 1 MB (W chunk-major units)
  float* csq = (float*)(wtgb + (size_t)128 * 4096 * 2);  // 16 KB
  float* xsq = csq + 4096;                      // 64 KB
  prep_x8<<<2048, 512, 0, stream>>>(x, xfs, xsq);
  prep_cen<<<1024, 256, 0, stream>>>(cen, cfr, csq);
  prep_w<<<64, 256, 0, stream>>>(W, wtgb);
  init_out<<<2048, 256, 0, stream>>>(b, (float*)d_out);
  rbf_main<<<512, 256, 0, stream>>>(xfs, cfr, wtgb, csq, xsq, (float*)d_out);
}